// Round 1
// baseline (150.095 us; speedup 1.0000x reference)
//
#include <hip/hip_runtime.h>
#include <hip/hip_bf16.h>

#define D_DIM 64
#define K_CODES 512

typedef _Float16 half8 __attribute__((ext_vector_type(8)));
typedef float f32x4 __attribute__((ext_vector_type(4)));

// ws layout: ee f32[512] @0 ; ET f32[512*64] @2048 B ; Bimg f16[512*64*2] @133120 B
#define WS_EE_OFF 0
#define WS_ET_OFF 2048
#define WS_BIMG_OFF 133120
#define WS_NEEDED (133120 + 131072)

// ---------------- prep: ee, ET (gather layout), Bimg (frag-ordered f16 hi/lo) ------------
// Parallelized 16x vs previous version (2 blocks -> 16 blocks, 4096 threads):
// thread u handles code k = u>>3, dim-chunk dc = u&7 (8 consecutive dims d = dc*8+j).
// For a fixed dc, ks = dc>>2 and g = dc&3 are constant, and j = d&7 runs 0..7 -> the 8
// Bimg f16 elements are CONTIGUOUS (n*8 + j) => one 16B half8 store for hi and one for lo.
// ET gets 8 consecutive floats (2x float4). ee reduced over the 8 dc-lanes via shfl_xor.
// Also zeroes the loss accumulator (saves the separate memset dispatch on the fast path).
__global__ __launch_bounds__(256) void vq3_prep(const float* __restrict__ E,
                                                float* __restrict__ ee,
                                                float* __restrict__ ET,
                                                _Float16* __restrict__ Bimg,
                                                float* __restrict__ loss_ptr) {
    const int u = blockIdx.x * 256 + threadIdx.x;   // [0, 4096)
    if (u == 0) *loss_ptr = 0.f;
    const int k = u >> 3;          // code 0..511
    const int dc = u & 7;          // dim-chunk 0..7
    const int t = k >> 4, n = k & 15;
    const int ks = dc >> 2, g = dc & 3;

    float v[8];
    float s = 0.f;
    half8 hi, lo;
#pragma unroll
    for (int j = 0; j < 8; ++j) {
        float e = E[(size_t)(dc * 8 + j) * K_CODES + k];
        v[j] = e;
        s = fmaf(e, e, s);
        _Float16 h = (_Float16)e;
        hi[j] = h;
        lo[j] = (_Float16)((e - (float)h) * 2048.0f);
    }
    f32x4* etp = (f32x4*)(ET + (size_t)k * D_DIM + dc * 8);
    etp[0] = (f32x4){v[0], v[1], v[2], v[3]};
    etp[1] = (f32x4){v[4], v[5], v[6], v[7]};
    _Float16* bp = Bimg + (size_t)t * 2048 + g * 128 + n * 8;
    *(half8*)(bp + ks * 512) = hi;            // part = ks (hi)
    *(half8*)(bp + (2 + ks) * 512) = lo;      // part = 2+ks (lo, pre-scaled by 2^11)
    // ee: sum the 8 dim-chunk partials (lanes u&7 are consecutive within the wave)
    s += __shfl_xor(s, 1);
    s += __shfl_xor(s, 2);
    s += __shfl_xor(s, 4);
    if (dc == 0) ee[k] = s;
}

// ---------------- main: 3-pass split-f16 MFMA, 32 tokens/wave, grid 1024 ------------
// Changes vs previous round:
//  * depth-2 B-fragment prefetch via 4 rotating register slots (issue tile t+2 while
//    computing tile t) -> ~2 compute-bodies (~330 cyc) of slack vs L2/L3 latency.
//  * non-temporal loads for the x stream and non-temporal stores for q, so the 66 MB
//    of streaming traffic stops evicting the hot 128 KB Bimg from per-XCD L2.
//  * __launch_bounds__(256,3): +2 B-slots costs ~34 VGPR; cap at ~170 so the compiler
//    never spills (still reaches 4 blocks/CU if allocation lands <=128).
__global__ __launch_bounds__(256, 3) void vq3_main(
        const float* __restrict__ x, const float* __restrict__ ee,
        const float* __restrict__ ET, const _Float16* __restrict__ Bimg,
        float* __restrict__ out_q, float* __restrict__ out_loss, float loss_scale) {
    __shared__ int idx_s[128];
    __shared__ float wsum_s[4];

    const int tid = threadIdx.x;
    const int l = tid & 63;            // lane
    const int w = tid >> 6;            // wave in block
    const int g = l >> 4;              // k-group quad (0..3)
    const int n = l & 15;              // A row / B col within tile
    const int bt0 = blockIdx.x * 128;  // block token base
    const int t0 = bt0 + w * 32;       // wave token base (32 tokens/wave)

    // ---- A fragments: 2 row-tiles x 2 k-steps, hi and lo(x2^11), held in regs all kernel
    half8 Ahi[2][2], Alo[2][2];
#pragma unroll
    for (int rt = 0; rt < 2; ++rt) {
#pragma unroll
        for (int ks = 0; ks < 2; ++ks) {
            const f32x4* xp = (const f32x4*)(x + (size_t)(t0 + rt * 16 + n) * D_DIM + ks * 32 + g * 8);
            f32x4 a = __builtin_nontemporal_load(xp);
            f32x4 b = __builtin_nontemporal_load(xp + 1);
            float va[8] = {a[0], a[1], a[2], a[3], b[0], b[1], b[2], b[3]};
            half8 h, lo;
#pragma unroll
            for (int j = 0; j < 8; ++j) {
                _Float16 hj = (_Float16)va[j];
                h[j] = hj;
                lo[j] = (_Float16)((va[j] - (float)hj) * 2048.0f);
            }
            Ahi[rt][ks] = h;
            Alo[rt][ks] = lo;
        }
    }

    // ---- running argmin state
    float bd[2][4];
    int bi[2][4];
#pragma unroll
    for (int i = 0; i < 2; ++i)
#pragma unroll
        for (int r = 0; r < 4; ++r) { bd[i][r] = 3.4e38f; bi[i][r] = 0; }

    const _Float16* bbase = Bimg + (size_t)g * 128 + n * 8;
    const float* eebase = ee + n;

#define DECL_SLOT(S) half8 S##h0, S##h1, S##l0, S##l1; float S##ee;
    DECL_SLOT(s0) DECL_SLOT(s1) DECL_SLOT(s2) DECL_SLOT(s3)

#define LOAD_SLOT(S, tile) { \
    const _Float16* bp_ = bbase + (size_t)(tile) * 2048; \
    S##h0 = *(const half8*)(bp_); \
    S##h1 = *(const half8*)(bp_ + 512); \
    S##l0 = *(const half8*)(bp_ + 1024); \
    S##l1 = *(const half8*)(bp_ + 1536); \
    S##ee = eebase[(tile) * 16]; }

#define COMPUTE_SLOT(S, tcur) { \
    f32x4 hh0 = {0.f, 0.f, 0.f, 0.f}, hh1 = {0.f, 0.f, 0.f, 0.f}; \
    f32x4 cr0 = {0.f, 0.f, 0.f, 0.f}, cr1 = {0.f, 0.f, 0.f, 0.f}; \
    hh0 = __builtin_amdgcn_mfma_f32_16x16x32_f16(Ahi[0][0], S##h0, hh0, 0, 0, 0); \
    hh0 = __builtin_amdgcn_mfma_f32_16x16x32_f16(Ahi[0][1], S##h1, hh0, 0, 0, 0); \
    hh1 = __builtin_amdgcn_mfma_f32_16x16x32_f16(Ahi[1][0], S##h0, hh1, 0, 0, 0); \
    hh1 = __builtin_amdgcn_mfma_f32_16x16x32_f16(Ahi[1][1], S##h1, hh1, 0, 0, 0); \
    cr0 = __builtin_amdgcn_mfma_f32_16x16x32_f16(Ahi[0][0], S##l0, cr0, 0, 0, 0); \
    cr0 = __builtin_amdgcn_mfma_f32_16x16x32_f16(Ahi[0][1], S##l1, cr0, 0, 0, 0); \
    cr0 = __builtin_amdgcn_mfma_f32_16x16x32_f16(Alo[0][0], S##h0, cr0, 0, 0, 0); \
    cr0 = __builtin_amdgcn_mfma_f32_16x16x32_f16(Alo[0][1], S##h1, cr0, 0, 0, 0); \
    cr1 = __builtin_amdgcn_mfma_f32_16x16x32_f16(Ahi[1][0], S##l0, cr1, 0, 0, 0); \
    cr1 = __builtin_amdgcn_mfma_f32_16x16x32_f16(Ahi[1][1], S##l1, cr1, 0, 0, 0); \
    cr1 = __builtin_amdgcn_mfma_f32_16x16x32_f16(Alo[1][0], S##h0, cr1, 0, 0, 0); \
    cr1 = __builtin_amdgcn_mfma_f32_16x16x32_f16(Alo[1][1], S##h1, cr1, 0, 0, 0); \
    const int code_ = (tcur) * 16 + n; \
    _Pragma("unroll") \
    for (int r = 0; r < 4; ++r) { \
        float d0_ = fmaf(4.8828125e-4f, cr0[r], hh0[r]); \
        float s0_ = fmaf(-2.f, d0_, S##ee); \
        bool c0_ = s0_ < bd[0][r]; \
        bd[0][r] = c0_ ? s0_ : bd[0][r]; \
        bi[0][r] = c0_ ? code_ : bi[0][r]; \
        float d1_ = fmaf(4.8828125e-4f, cr1[r], hh1[r]); \
        float s1_ = fmaf(-2.f, d1_, S##ee); \
        bool c1_ = s1_ < bd[1][r]; \
        bd[1][r] = c1_ ? s1_ : bd[1][r]; \
        bi[1][r] = c1_ ? code_ : bi[1][r]; \
    } }

    // prologue: tiles 0,1 in flight
    LOAD_SLOT(s0, 0)
    LOAD_SLOT(s1, 1)
    // steady state: before computing slot X for tile T, its loads were issued 2 bodies ago.
    // Tail prefetches wrap to tiles 0/1 (&31) -- data unused, just keeps addresses in-bounds.
#pragma unroll 1
    for (int t = 0; t < 32; t += 4) {
        LOAD_SLOT(s2, t + 2)
        COMPUTE_SLOT(s0, t)
        LOAD_SLOT(s3, t + 3)
        COMPUTE_SLOT(s1, t + 1)
        LOAD_SLOT(s0, (t + 4) & 31)
        COMPUTE_SLOT(s2, t + 2)
        LOAD_SLOT(s1, (t + 5) & 31)
        COMPUTE_SLOT(s3, t + 3)
    }
#undef DECL_SLOT
#undef LOAD_SLOT
#undef COMPUTE_SLOT

    // ---- cross-lane argmin over the 16 code-columns (reduce over lane bits 0..3)
#pragma unroll
    for (int mask = 1; mask < 16; mask <<= 1) {
#pragma unroll
        for (int rt = 0; rt < 2; ++rt)
#pragma unroll
            for (int r = 0; r < 4; ++r) {
                float od = __shfl_xor(bd[rt][r], mask);
                int oi = __shfl_xor(bi[rt][r], mask);
                if (od < bd[rt][r] || (od == bd[rt][r] && oi < bi[rt][r])) { bd[rt][r] = od; bi[rt][r] = oi; }
            }
    }
    if (n == 0) {
#pragma unroll
        for (int rt = 0; rt < 2; ++rt)
#pragma unroll
            for (int r = 0; r < 4; ++r)
                idx_s[w * 32 + rt * 16 + g * 4 + r] = bi[rt][r];   // C-layout: row = g*4 + r
    }
    __syncthreads();

    // ---- epilogue: gather q, write coalesced (non-temporal), loss partial
    float lsum = 0.f;
#pragma unroll
    for (int p = 0; p < 2; ++p) {
        const int tok = p * 64 + (tid >> 2);
        const int part = tid & 3;
        const int gidx = idx_s[tok];
        const size_t qoff = (size_t)(bt0 + tok) * D_DIM + part * 16;
        const f32x4* ep = (const f32x4*)(ET + (size_t)gidx * D_DIM + part * 16);
        const f32x4* xp = (const f32x4*)(x + qoff);
        f32x4* qp = (f32x4*)(out_q + qoff);
#pragma unroll
        for (int u = 0; u < 4; ++u) {
            f32x4 qv = ep[u];
            f32x4 xv = __builtin_nontemporal_load(xp + u);
            f32x4 dv = qv - xv;
            lsum = fmaf(dv[0], dv[0], lsum);
            lsum = fmaf(dv[1], dv[1], lsum);
            lsum = fmaf(dv[2], dv[2], lsum);
            lsum = fmaf(dv[3], dv[3], lsum);
            __builtin_nontemporal_store(qv, qp + u);
        }
    }
#pragma unroll
    for (int mask = 1; mask < 64; mask <<= 1) lsum += __shfl_xor(lsum, mask);
    if (l == 0) wsum_s[w] = lsum;
    __syncthreads();
    if (tid == 0) atomicAdd(out_loss, (wsum_s[0] + wsum_s[1] + wsum_s[2] + wsum_s[3]) * loss_scale);
}

// =================== round-1 fallback (proven) ===================
#define TOK_TILE 64
#define CHUNK 64
#define NCHUNK (K_CODES / CHUNK)
#define XS_STRIDE (TOK_TILE + 4)

__global__ __launch_bounds__(256, 4) void vq_fb_main(
        const float* __restrict__ x, const float* __restrict__ E,
        float* __restrict__ out_q, float* __restrict__ out_loss, float loss_scale) {
    __shared__ __align__(16) float Xs[D_DIM][XS_STRIDE];
    __shared__ __align__(16) float Es[D_DIM][CHUNK];
    __shared__ float ee_s[K_CODES];
    __shared__ int idx_s[TOK_TILE];
    __shared__ float wsum_s[4];

    const int tid = threadIdx.x;
    const int t0 = blockIdx.x * TOK_TILE;
    const int tx = tid & 15, ty = tid >> 4;
    const int ty4 = ty * 4, tx4 = tx * 4;

#pragma unroll
    for (int it = 0; it < 4; ++it) {
        int tl = it * 16 + (tid >> 4);
        int d0 = (tid & 15) * 4;
        float4 v = *(const float4*)(x + (size_t)(t0 + tl) * D_DIM + d0);
        Xs[d0 + 0][tl] = v.x; Xs[d0 + 1][tl] = v.y; Xs[d0 + 2][tl] = v.z; Xs[d0 + 3][tl] = v.w;
    }
    for (int k = tid; k < K_CODES; k += 256) {
        float s = 0.f;
#pragma unroll
        for (int d = 0; d < D_DIM; ++d) { float v = E[(size_t)d * K_CODES + k]; s = fmaf(v, v, s); }
        ee_s[k] = s;
    }

    float bd[4] = {3.4e38f, 3.4e38f, 3.4e38f, 3.4e38f};
    int bi[4] = {0, 0, 0, 0};

    for (int c = 0; c < NCHUNK; ++c) {
        __syncthreads();
#pragma unroll
        for (int ww = 0; ww < 4; ++ww) {
            int fidx = ww * 256 + tid;
            int d = fidx >> 4, k0 = (fidx & 15) * 4;
            float4 v = *(const float4*)(E + (size_t)d * K_CODES + c * CHUNK + k0);
            *(float4*)&Es[d][k0] = v;
        }
        __syncthreads();
        float acc[4][4] = {};
#pragma unroll
        for (int d = 0; d < D_DIM; ++d) {
            float4 a = *(const float4*)&Xs[d][ty4];
            float4 b = *(const float4*)&Es[d][tx4];
            acc[0][0] = fmaf(a.x, b.x, acc[0][0]); acc[0][1] = fmaf(a.x, b.y, acc[0][1]);
            acc[0][2] = fmaf(a.x, b.z, acc[0][2]); acc[0][3] = fmaf(a.x, b.w, acc[0][3]);
            acc[1][0] = fmaf(a.y, b.x, acc[1][0]); acc[1][1] = fmaf(a.y, b.y, acc[1][1]);
            acc[1][2] = fmaf(a.y, b.z, acc[1][2]); acc[1][3] = fmaf(a.y, b.w, acc[1][3]);
            acc[2][0] = fmaf(a.z, b.x, acc[2][0]); acc[2][1] = fmaf(a.z, b.y, acc[2][1]);
            acc[2][2] = fmaf(a.z, b.z, acc[2][2]); acc[2][3] = fmaf(a.z, b.w, acc[2][3]);
            acc[3][0] = fmaf(a.w, b.x, acc[3][0]); acc[3][1] = fmaf(a.w, b.y, acc[3][1]);
            acc[3][2] = fmaf(a.w, b.z, acc[3][2]); acc[3][3] = fmaf(a.w, b.w, acc[3][3]);
        }
        const int kbase = c * CHUNK + tx4;
#pragma unroll
        for (int i = 0; i < 4; ++i)
#pragma unroll
            for (int j = 0; j < 4; ++j) {
                float s = fmaf(-2.f, acc[i][j], ee_s[kbase + j]);
                if (s < bd[i]) { bd[i] = s; bi[i] = kbase + j; }
            }
    }
#pragma unroll
    for (int mask = 1; mask < 16; mask <<= 1)
#pragma unroll
        for (int i = 0; i < 4; ++i) {
            float od = __shfl_xor(bd[i], mask);
            int oi = __shfl_xor(bi[i], mask);
            if (od < bd[i] || (od == bd[i] && oi < bi[i])) { bd[i] = od; bi[i] = oi; }
        }
    if (tx == 0)
#pragma unroll
        for (int i = 0; i < 4; ++i) idx_s[ty4 + i] = bi[i];
    __syncthreads();

    const int tok = tid >> 2, part = tid & 3;
    const int gidx = idx_s[tok];
    const int gt = t0 + tok;
    float lsum = 0.f;
#pragma unroll
    for (int ww = 0; ww < 4; ++ww) {
        int o = part * 16 + ww * 4;
        float4 qv;
        qv.x = E[(size_t)(o + 0) * K_CODES + gidx];
        qv.y = E[(size_t)(o + 1) * K_CODES + gidx];
        qv.z = E[(size_t)(o + 2) * K_CODES + gidx];
        qv.w = E[(size_t)(o + 3) * K_CODES + gidx];
        float4 xv;
        xv.x = Xs[o + 0][tok]; xv.y = Xs[o + 1][tok]; xv.z = Xs[o + 2][tok]; xv.w = Xs[o + 3][tok];
        float dx = qv.x - xv.x, dy = qv.y - xv.y, dz = qv.z - xv.z, dw = qv.w - xv.w;
        lsum = fmaf(dx, dx, lsum); lsum = fmaf(dy, dy, lsum);
        lsum = fmaf(dz, dz, lsum); lsum = fmaf(dw, dw, lsum);
        *(float4*)(out_q + (size_t)gt * D_DIM + o) = qv;
    }
#pragma unroll
    for (int mask = 1; mask < 64; mask <<= 1) lsum += __shfl_xor(lsum, mask);
    if ((tid & 63) == 0) wsum_s[tid >> 6] = lsum;
    __syncthreads();
    if (tid == 0) atomicAdd(out_loss, (wsum_s[0] + wsum_s[1] + wsum_s[2] + wsum_s[3]) * loss_scale);
}

extern "C" void kernel_launch(void* const* d_in, const int* in_sizes, int n_in,
                              void* d_out, int out_size, void* d_ws, size_t ws_size,
                              hipStream_t stream) {
    const float* x = (const float*)d_in[0];   // [B,T,D] fp32
    const float* E = (const float*)d_in[1];   // [D,K] fp32
    float* out = (float*)d_out;
    const int n_tok = in_sizes[0] / D_DIM;    // 131072
    float* loss_ptr = out + (out_size - 1);
    const float loss_scale = 2.0f / (float)(n_tok * D_DIM);

    if (ws_size >= (size_t)WS_NEEDED) {
        float* ee = (float*)((char*)d_ws + WS_EE_OFF);
        float* ET = (float*)((char*)d_ws + WS_ET_OFF);
        _Float16* Bimg = (_Float16*)((char*)d_ws + WS_BIMG_OFF);
        vq3_prep<<<16, 256, 0, stream>>>(E, ee, ET, Bimg, loss_ptr);   // loss zeroed in prep
        vq3_main<<<n_tok / 128, 256, 0, stream>>>(x, ee, ET, Bimg, out, loss_ptr, loss_scale);
    } else {
        hipMemsetAsync(loss_ptr, 0, sizeof(float), stream);
        vq_fb_main<<<n_tok / TOK_TILE, 256, 0, stream>>>(x, E, out, loss_ptr, loss_scale);
    }
}

// Round 2
// 119.088 us; speedup vs baseline: 1.2604x; 1.2604x over previous
//
#include <hip/hip_runtime.h>
#include <hip/hip_bf16.h>

#define D_DIM 64
#define K_CODES 512

typedef _Float16 half8 __attribute__((ext_vector_type(8)));
typedef float f32x4 __attribute__((ext_vector_type(4)));

// ws layout: ee f32[512] @0 ; ET f32[512*64] @2048 B ; Bimg f16[512*64*2] @133120 B
#define WS_EE_OFF 0
#define WS_ET_OFF 2048
#define WS_BIMG_OFF 133120
#define WS_NEEDED (133120 + 131072)

// ---------------- prep: ee, ET (gather layout), Bimg (frag-ordered f16 hi/lo) ------------
// (proven in round 1) thread u: code k = u>>3, dim-chunk dc = u&7. Coalesced half8/f32x4
// stores; ee reduced over the 8 dc-lanes via shfl_xor. Zeroes the loss accumulator.
__global__ __launch_bounds__(256) void vq3_prep(const float* __restrict__ E,
                                                float* __restrict__ ee,
                                                float* __restrict__ ET,
                                                _Float16* __restrict__ Bimg,
                                                float* __restrict__ loss_ptr) {
    const int u = blockIdx.x * 256 + threadIdx.x;   // [0, 4096)
    if (u == 0) *loss_ptr = 0.f;
    const int k = u >> 3;          // code 0..511
    const int dc = u & 7;          // dim-chunk 0..7
    const int t = k >> 4, n = k & 15;
    const int ks = dc >> 2, g = dc & 3;

    float v[8];
    float s = 0.f;
    half8 hi, lo;
#pragma unroll
    for (int j = 0; j < 8; ++j) {
        float e = E[(size_t)(dc * 8 + j) * K_CODES + k];
        v[j] = e;
        s = fmaf(e, e, s);
        _Float16 h = (_Float16)e;
        hi[j] = h;
        lo[j] = (_Float16)((e - (float)h) * 2048.0f);
    }
    f32x4* etp = (f32x4*)(ET + (size_t)k * D_DIM + dc * 8);
    etp[0] = (f32x4){v[0], v[1], v[2], v[3]};
    etp[1] = (f32x4){v[4], v[5], v[6], v[7]};
    _Float16* bp = Bimg + (size_t)t * 2048 + g * 128 + n * 8;
    *(half8*)(bp + ks * 512) = hi;            // part = ks (hi)
    *(half8*)(bp + (2 + ks) * 512) = lo;      // part = 2+ks (lo, pre-scaled by 2^11)
    s += __shfl_xor(s, 1);
    s += __shfl_xor(s, 2);
    s += __shfl_xor(s, 4);
    if (dc == 0) ee[k] = s;
}

// ---------------- main: 3-pass split-f16 MFMA, 64 tokens/wave (rt=4), grid 512 ------------
// Theory: the t-loop is L2-BANDWIDTH-bound on Bimg re-reads (128 KB per wave). rt=2->4
// halves Bimg L2 traffic per token (64 MB -> 32 MB per XCD) and doubles the compute body
// (~24 MFMA + ~64 VALU >= 300 cyc), covering L2 latency with the proven 1-deep prefetch.
// Loss is computed as bd_min + ||x||^2 (both already in registers) so the epilogue never
// re-reads x from HBM (-33.5 MB). No non-temporal ops (round-1 nt stores doubled WRITE_SIZE).
// VGPR ~176 -> 2 waves/SIMD; grid 512 = 2 blocks/CU = 8 waves/CU, exactly matching.
__global__ __launch_bounds__(256, 2) void vq3_main(
        const float* __restrict__ x, const float* __restrict__ ee,
        const float* __restrict__ ET, const _Float16* __restrict__ Bimg,
        float* __restrict__ out_q, float* __restrict__ out_loss, float loss_scale) {
    __shared__ int idx_s[256];
    __shared__ float wsum_s[4];

    const int tid = threadIdx.x;
    const int l = tid & 63;            // lane
    const int w = tid >> 6;            // wave in block
    const int g = l >> 4;              // k-group quad (0..3)
    const int n = l & 15;              // A row / B col within tile
    const int bt0 = blockIdx.x * 256;  // block token base
    const int t0 = bt0 + w * 64;       // wave token base (64 tokens/wave)

    // ---- A fragments: 4 row-tiles x 2 k-steps, hi and lo(x2^11), held in regs all kernel.
    // Also accumulate ||x||^2 per token (xx[rt], reduced over the 4 g-lane-groups).
    half8 Ahi[4][2], Alo[4][2];
    float xx[4];
#pragma unroll
    for (int rt = 0; rt < 4; ++rt) {
        float xs = 0.f;
#pragma unroll
        for (int ks = 0; ks < 2; ++ks) {
            const f32x4* xp = (const f32x4*)(x + (size_t)(t0 + rt * 16 + n) * D_DIM + ks * 32 + g * 8);
            f32x4 a = xp[0], b = xp[1];
            float va[8] = {a[0], a[1], a[2], a[3], b[0], b[1], b[2], b[3]};
            half8 h, lo;
#pragma unroll
            for (int j = 0; j < 8; ++j) {
                _Float16 hj = (_Float16)va[j];
                h[j] = hj;
                lo[j] = (_Float16)((va[j] - (float)hj) * 2048.0f);
                xs = fmaf(va[j], va[j], xs);
            }
            Ahi[rt][ks] = h;
            Alo[rt][ks] = lo;
        }
        // reduce the 8-dim chunk sums over g (lane bits 4,5): all lanes get ||x_tok(rt*16+n)||^2
        xs += __shfl_xor(xs, 16);
        xs += __shfl_xor(xs, 32);
        xx[rt] = xs;
    }

    // ---- running argmin state
    float bd[4][4];
    int bi[4][4];
#pragma unroll
    for (int i = 0; i < 4; ++i)
#pragma unroll
        for (int r = 0; r < 4; ++r) { bd[i][r] = 3.4e38f; bi[i][r] = 0; }

    // ---- B-frag pointers; prefetch tile 0 (proven 1-deep prefetch structure)
    const _Float16* bbase = Bimg + (size_t)g * 128 + n * 8;
    half8 Bh0, Bh1, Bl0, Bl1;
    float eev;
    {
        Bh0 = *(const half8*)(bbase + 0 * 512);
        Bh1 = *(const half8*)(bbase + 1 * 512);
        Bl0 = *(const half8*)(bbase + 2 * 512);
        Bl1 = *(const half8*)(bbase + 3 * 512);
        eev = ee[n];
    }

#pragma unroll 2
    for (int t = 0; t < 32; ++t) {
        // prefetch next tile (wraps harmlessly to tile 0 on last iter)
        const int tn = (t + 1) & 31;
        const _Float16* bn = bbase + (size_t)tn * 2048;
        half8 Nh0 = *(const half8*)(bn + 0 * 512);
        half8 Nh1 = *(const half8*)(bn + 1 * 512);
        half8 Nl0 = *(const half8*)(bn + 2 * 512);
        half8 Nl1 = *(const half8*)(bn + 3 * 512);
        float een = ee[tn * 16 + n];

        f32x4 hh[4], cr[4];
#pragma unroll
        for (int rt = 0; rt < 4; ++rt) { hh[rt] = (f32x4){0.f, 0.f, 0.f, 0.f}; cr[rt] = (f32x4){0.f, 0.f, 0.f, 0.f}; }
#pragma unroll
        for (int rt = 0; rt < 4; ++rt) {
            hh[rt] = __builtin_amdgcn_mfma_f32_16x16x32_f16(Ahi[rt][0], Bh0, hh[rt], 0, 0, 0);
            hh[rt] = __builtin_amdgcn_mfma_f32_16x16x32_f16(Ahi[rt][1], Bh1, hh[rt], 0, 0, 0);
            cr[rt] = __builtin_amdgcn_mfma_f32_16x16x32_f16(Ahi[rt][0], Bl0, cr[rt], 0, 0, 0);
            cr[rt] = __builtin_amdgcn_mfma_f32_16x16x32_f16(Ahi[rt][1], Bl1, cr[rt], 0, 0, 0);
            cr[rt] = __builtin_amdgcn_mfma_f32_16x16x32_f16(Alo[rt][0], Bh0, cr[rt], 0, 0, 0);
            cr[rt] = __builtin_amdgcn_mfma_f32_16x16x32_f16(Alo[rt][1], Bh1, cr[rt], 0, 0, 0);
        }

        const int code = t * 16 + n;   // this lane's code column
#pragma unroll
        for (int rt = 0; rt < 4; ++rt) {
#pragma unroll
            for (int r = 0; r < 4; ++r) {
                float dot = fmaf(4.8828125e-4f, cr[rt][r], hh[rt][r]);  // hh + cross*2^-11
                float s = fmaf(-2.f, dot, eev);
                if (s < bd[rt][r]) { bd[rt][r] = s; bi[rt][r] = code; }
            }
        }

        Bh0 = Nh0; Bh1 = Nh1; Bl0 = Nl0; Bl1 = Nl1; eev = een;
    }

    // ---- cross-lane argmin over the 16 code-columns (reduce over lane bits 0..3)
#pragma unroll
    for (int mask = 1; mask < 16; mask <<= 1) {
#pragma unroll
        for (int rt = 0; rt < 4; ++rt)
#pragma unroll
            for (int r = 0; r < 4; ++r) {
                float od = __shfl_xor(bd[rt][r], mask);
                int oi = __shfl_xor(bi[rt][r], mask);
                if (od < bd[rt][r] || (od == bd[rt][r] && oi < bi[rt][r])) { bd[rt][r] = od; bi[rt][r] = oi; }
            }
    }
    if (n == 0) {
#pragma unroll
        for (int rt = 0; rt < 4; ++rt)
#pragma unroll
            for (int r = 0; r < 4; ++r)
                idx_s[w * 64 + rt * 16 + g * 4 + r] = bi[rt][r];   // C-layout: row = g*4 + r
    }

    // ---- loss WITHOUT re-reading x: dist = bd_min + ||x||^2.
    // bd[rt][r] (post-reduction, replicated over n) is the min of ee - 2*dot for token
    // row g*4+r of tile rt; xx for that token lives in lane (g*4+r) (replicated over its
    // own g-bits). All lanes run the shuffle; only n==0 lanes accumulate (1 per token).
    float lsum = 0.f;
#pragma unroll
    for (int rt = 0; rt < 4; ++rt)
#pragma unroll
        for (int r = 0; r < 4; ++r) {
            float xv = __shfl(xx[rt], g * 4 + r);
            float dist = bd[rt][r] + xv;
            if (n == 0) lsum += dist;
        }
    __syncthreads();

    // ---- epilogue: gather q from ET (L2-hot), write coalesced. No x traffic.
#pragma unroll
    for (int p = 0; p < 4; ++p) {
        const int tok = p * 64 + (tid >> 2);
        const int part = tid & 3;
        const int gidx = idx_s[tok];
        const f32x4* ep = (const f32x4*)(ET + (size_t)gidx * D_DIM + part * 16);
        f32x4* qp = (f32x4*)(out_q + (size_t)(bt0 + tok) * D_DIM + part * 16);
#pragma unroll
        for (int u = 0; u < 4; ++u) qp[u] = ep[u];
    }

#pragma unroll
    for (int mask = 1; mask < 64; mask <<= 1) lsum += __shfl_xor(lsum, mask);
    if (l == 0) wsum_s[w] = lsum;
    __syncthreads();
    if (tid == 0) atomicAdd(out_loss, (wsum_s[0] + wsum_s[1] + wsum_s[2] + wsum_s[3]) * loss_scale);
}

// =================== round-1 fallback (proven) ===================
#define TOK_TILE 64
#define CHUNK 64
#define NCHUNK (K_CODES / CHUNK)
#define XS_STRIDE (TOK_TILE + 4)

__global__ __launch_bounds__(256, 4) void vq_fb_main(
        const float* __restrict__ x, const float* __restrict__ E,
        float* __restrict__ out_q, float* __restrict__ out_loss, float loss_scale) {
    __shared__ __align__(16) float Xs[D_DIM][XS_STRIDE];
    __shared__ __align__(16) float Es[D_DIM][CHUNK];
    __shared__ float ee_s[K_CODES];
    __shared__ int idx_s[TOK_TILE];
    __shared__ float wsum_s[4];

    const int tid = threadIdx.x;
    const int t0 = blockIdx.x * TOK_TILE;
    const int tx = tid & 15, ty = tid >> 4;
    const int ty4 = ty * 4, tx4 = tx * 4;

#pragma unroll
    for (int it = 0; it < 4; ++it) {
        int tl = it * 16 + (tid >> 4);
        int d0 = (tid & 15) * 4;
        float4 v = *(const float4*)(x + (size_t)(t0 + tl) * D_DIM + d0);
        Xs[d0 + 0][tl] = v.x; Xs[d0 + 1][tl] = v.y; Xs[d0 + 2][tl] = v.z; Xs[d0 + 3][tl] = v.w;
    }
    for (int k = tid; k < K_CODES; k += 256) {
        float s = 0.f;
#pragma unroll
        for (int d = 0; d < D_DIM; ++d) { float v = E[(size_t)d * K_CODES + k]; s = fmaf(v, v, s); }
        ee_s[k] = s;
    }

    float bd[4] = {3.4e38f, 3.4e38f, 3.4e38f, 3.4e38f};
    int bi[4] = {0, 0, 0, 0};

    for (int c = 0; c < NCHUNK; ++c) {
        __syncthreads();
#pragma unroll
        for (int ww = 0; ww < 4; ++ww) {
            int fidx = ww * 256 + tid;
            int d = fidx >> 4, k0 = (fidx & 15) * 4;
            float4 v = *(const float4*)(E + (size_t)d * K_CODES + c * CHUNK + k0);
            *(float4*)&Es[d][k0] = v;
        }
        __syncthreads();
        float acc[4][4] = {};
#pragma unroll
        for (int d = 0; d < D_DIM; ++d) {
            float4 a = *(const float4*)&Xs[d][ty4];
            float4 b = *(const float4*)&Es[d][tx4];
            acc[0][0] = fmaf(a.x, b.x, acc[0][0]); acc[0][1] = fmaf(a.x, b.y, acc[0][1]);
            acc[0][2] = fmaf(a.x, b.z, acc[0][2]); acc[0][3] = fmaf(a.x, b.w, acc[0][3]);
            acc[1][0] = fmaf(a.y, b.x, acc[1][0]); acc[1][1] = fmaf(a.y, b.y, acc[1][1]);
            acc[1][2] = fmaf(a.y, b.z, acc[1][2]); acc[1][3] = fmaf(a.y, b.w, acc[1][3]);
            acc[2][0] = fmaf(a.z, b.x, acc[2][0]); acc[2][1] = fmaf(a.z, b.y, acc[2][1]);
            acc[2][2] = fmaf(a.z, b.z, acc[2][2]); acc[2][3] = fmaf(a.z, b.w, acc[2][3]);
            acc[3][0] = fmaf(a.w, b.x, acc[3][0]); acc[3][1] = fmaf(a.w, b.y, acc[3][1]);
            acc[3][2] = fmaf(a.w, b.z, acc[3][2]); acc[3][3] = fmaf(a.w, b.w, acc[3][3]);
        }
        const int kbase = c * CHUNK + tx4;
#pragma unroll
        for (int i = 0; i < 4; ++i)
#pragma unroll
            for (int j = 0; j < 4; ++j) {
                float s = fmaf(-2.f, acc[i][j], ee_s[kbase + j]);
                if (s < bd[i]) { bd[i] = s; bi[i] = kbase + j; }
            }
    }
#pragma unroll
    for (int mask = 1; mask < 16; mask <<= 1)
#pragma unroll
        for (int i = 0; i < 4; ++i) {
            float od = __shfl_xor(bd[i], mask);
            int oi = __shfl_xor(bi[i], mask);
            if (od < bd[i] || (od == bd[i] && oi < bi[i])) { bd[i] = od; bi[i] = oi; }
        }
    if (tx == 0)
#pragma unroll
        for (int i = 0; i < 4; ++i) idx_s[ty4 + i] = bi[i];
    __syncthreads();

    const int tok = tid >> 2, part = tid & 3;
    const int gidx = idx_s[tok];
    const int gt = t0 + tok;
    float lsum = 0.f;
#pragma unroll
    for (int ww = 0; ww < 4; ++ww) {
        int o = part * 16 + ww * 4;
        float4 qv;
        qv.x = E[(size_t)(o + 0) * K_CODES + gidx];
        qv.y = E[(size_t)(o + 1) * K_CODES + gidx];
        qv.z = E[(size_t)(o + 2) * K_CODES + gidx];
        qv.w = E[(size_t)(o + 3) * K_CODES + gidx];
        float4 xv;
        xv.x = Xs[o + 0][tok]; xv.y = Xs[o + 1][tok]; xv.z = Xs[o + 2][tok]; xv.w = Xs[o + 3][tok];
        float dx = qv.x - xv.x, dy = qv.y - xv.y, dz = qv.z - xv.z, dw = qv.w - xv.w;
        lsum = fmaf(dx, dx, lsum); lsum = fmaf(dy, dy, lsum);
        lsum = fmaf(dz, dz, lsum); lsum = fmaf(dw, dw, lsum);
        *(float4*)(out_q + (size_t)gt * D_DIM + o) = qv;
    }
#pragma unroll
    for (int mask = 1; mask < 64; mask <<= 1) lsum += __shfl_xor(lsum, mask);
    if ((tid & 63) == 0) wsum_s[tid >> 6] = lsum;
    __syncthreads();
    if (tid == 0) atomicAdd(out_loss, (wsum_s[0] + wsum_s[1] + wsum_s[2] + wsum_s[3]) * loss_scale);
}

extern "C" void kernel_launch(void* const* d_in, const int* in_sizes, int n_in,
                              void* d_out, int out_size, void* d_ws, size_t ws_size,
                              hipStream_t stream) {
    const float* x = (const float*)d_in[0];   // [B,T,D] fp32
    const float* E = (const float*)d_in[1];   // [D,K] fp32
    float* out = (float*)d_out;
    const int n_tok = in_sizes[0] / D_DIM;    // 131072
    float* loss_ptr = out + (out_size - 1);
    const float loss_scale = 2.0f / (float)(n_tok * D_DIM);

    if (ws_size >= (size_t)WS_NEEDED) {
        float* ee = (float*)((char*)d_ws + WS_EE_OFF);
        float* ET = (float*)((char*)d_ws + WS_ET_OFF);
        _Float16* Bimg = (_Float16*)((char*)d_ws + WS_BIMG_OFF);
        vq3_prep<<<16, 256, 0, stream>>>(E, ee, ET, Bimg, loss_ptr);   // loss zeroed in prep
        vq3_main<<<n_tok / 256, 256, 0, stream>>>(x, ee, ET, Bimg, out, loss_ptr, loss_scale);
    } else {
        hipMemsetAsync(loss_ptr, 0, sizeof(float), stream);
        vq_fb_main<<<n_tok / TOK_TILE, 256, 0, stream>>>(x, E, out, loss_ptr, loss_scale);
    }
}